// Round 1
// baseline (857.500 us; speedup 1.0000x reference)
//
#include <hip/hip_runtime.h>
#include <stdint.h>

// Problem constants (fixed by setup_inputs)
#define B_ 8
#define T_ 4096
#define D_ 1024
#define S_ 64
#define N_ 32768            // B*T
#define OUT_ELEMS 33554432  // N*D

typedef __attribute__((ext_vector_type(8))) short bf16x8;
typedef __attribute__((ext_vector_type(4))) float f32x4;

__device__ __forceinline__ uint16_t f2bf(float f) {
    union { float f; uint32_t u; } v; v.f = f;
    uint32_t r = v.u + 0x7FFFu + ((v.u >> 16) & 1u);
    return (uint16_t)(r >> 16);
}
__device__ __forceinline__ float bf2f(uint16_t h) {
    union { uint32_t u; float f; } v; v.u = ((uint32_t)h) << 16;
    return v.f;
}

// ---------------- cast fp32 -> bf16, vectorized (float4 in, ushort4 out) ----
__global__ void cast_f32_bf16(const float* __restrict__ src,
                              uint16_t* __restrict__ dst, int n4) {
    int i = blockIdx.x * blockDim.x + threadIdx.x;
    if (i >= n4) return;
    float4 v = ((const float4*)src)[i];
    ushort4 o;
    o.x = f2bf(v.x); o.y = f2bf(v.y); o.z = f2bf(v.z); o.w = f2bf(v.w);
    ((ushort4*)dst)[i] = o;
}

// ---------------- K1: x_shift = (x_cat @ Wshift^T)*g + x*(1-g)  -> bf16 ----
// grid (8, 256): x = N-tile (8 x 128 cols), y = M-tile (256 x 128 rows)
__global__ __launch_bounds__(256) void k1_shift_gemm(
    const uint16_t* __restrict__ xb, const uint16_t* __restrict__ Wsb,
    const float* __restrict__ shift_gate, uint16_t* __restrict__ xs)
{
    const int tid = threadIdx.x;
    const int w = tid >> 6, lane = tid & 63, quad = lane >> 4, l16 = lane & 15;
    const int wm = w >> 1, wn = w & 1;
    const int m0 = blockIdx.y * 128 + wm * 64;
    const int n0 = blockIdx.x * 128 + wn * 64;

    const uint16_t* aptr[4];
    const uint16_t* bptr[4];
#pragma unroll
    for (int i = 0; i < 4; ++i) {
        int row = m0 + i * 16 + l16;
        aptr[i] = xb + (size_t)(row ^ 2048) * D_ + quad * 8;   // x_cat[t]=x[t^2048]
        bptr[i] = Wsb + (size_t)(n0 + i * 16 + l16) * D_ + quad * 8;
    }

    f32x4 acc[4][4];
#pragma unroll
    for (int i = 0; i < 4; ++i)
#pragma unroll
        for (int j = 0; j < 4; ++j) acc[i][j] = (f32x4){0.f, 0.f, 0.f, 0.f};

    for (int k = 0; k < D_; k += 32) {
        bf16x8 a[4], b[4];
#pragma unroll
        for (int i = 0; i < 4; ++i) a[i] = *(const bf16x8*)(aptr[i] + k);
#pragma unroll
        for (int i = 0; i < 4; ++i) b[i] = *(const bf16x8*)(bptr[i] + k);
#pragma unroll
        for (int i = 0; i < 4; ++i)
#pragma unroll
            for (int j = 0; j < 4; ++j)
                acc[i][j] = __builtin_amdgcn_mfma_f32_16x16x32_bf16(
                    a[i], b[j], acc[i][j], 0, 0, 0);
    }

#pragma unroll
    for (int j = 0; j < 4; ++j) {
        int col = n0 + j * 16 + l16;
        float g = 1.f / (1.f + __expf(-shift_gate[col]));
        float omg = 1.f - g;
#pragma unroll
        for (int i = 0; i < 4; ++i) {
            int row = m0 + i * 16 + quad * 4;
#pragma unroll
            for (int r = 0; r < 4; ++r) {
                float res = acc[i][j][r] * g +
                            bf2f(xb[(size_t)(row + r) * D_ + col]) * omg;
                xs[(size_t)(row + r) * D_ + col] = f2bf(res);
            }
        }
    }
}

// ---------------- K2: layernorm in-place on xs (bf16) ----------------------
__global__ __launch_bounds__(256) void k2_ln(uint16_t* __restrict__ xs,
                                             const float* __restrict__ ln_w,
                                             const float* __restrict__ ln_b)
{
    const int row = blockIdx.x;
    const int tid = threadIdx.x;
    const int w = tid >> 6, lane = tid & 63;
    uint16_t* p = xs + (size_t)row * D_;

    ushort4 h = ((const ushort4*)p)[tid];
    float v0 = bf2f(h.x), v1 = bf2f(h.y), v2 = bf2f(h.z), v3 = bf2f(h.w);
    float s = v0 + v1 + v2 + v3;
    float q = v0 * v0 + v1 * v1 + v2 * v2 + v3 * v3;
#pragma unroll
    for (int off = 32; off > 0; off >>= 1) {
        s += __shfl_xor(s, off);
        q += __shfl_xor(q, off);
    }
    __shared__ float rs[4], rq[4];
    if (lane == 0) { rs[w] = s; rq[w] = q; }
    __syncthreads();
    float tot = rs[0] + rs[1] + rs[2] + rs[3];
    float totq = rq[0] + rq[1] + rq[2] + rq[3];
    float mu = tot * (1.f / D_);
    float var = totq * (1.f / D_) - mu * mu;
    float rstd = rsqrtf(var + 1e-5f);

    float4 lw = ((const float4*)ln_w)[tid];
    float4 lb = ((const float4*)ln_b)[tid];
    ushort4 o;
    o.x = f2bf((v0 - mu) * rstd * lw.x + lb.x);
    o.y = f2bf((v1 - mu) * rstd * lw.y + lb.y);
    o.z = f2bf((v2 - mu) * rstd * lw.z + lb.z);
    o.w = f2bf((v3 - mu) * rstd * lw.w + lb.w);
    ((ushort4*)p)[tid] = o;
}

// ---------------- K3: k/v projection + wkv  (M=32768, N=128, K=1024) -------
// grid 256 blocks of 256 thr; waves: wn=0 -> k (W_key), wn=1 -> v (W_value)
__global__ __launch_bounds__(256) void k3_kv(
    const uint16_t* __restrict__ xn, const uint16_t* __restrict__ Wkvb,
    const float* __restrict__ time_first, float* __restrict__ wkv)
{
    __shared__ float tile[2][128][65];
    const int tid = threadIdx.x;
    const int w = tid >> 6, lane = tid & 63, quad = lane >> 4, l16 = lane & 15;
    const int wm = w >> 1, wn = w & 1;
    const int bm0 = blockIdx.x * 128;
    const int m0 = bm0 + wm * 64;

    const uint16_t* aptr[4];
    const uint16_t* bptr[4];
#pragma unroll
    for (int i = 0; i < 4; ++i) {
        aptr[i] = xn + (size_t)(m0 + i * 16 + l16) * D_ + quad * 8;
        bptr[i] = Wkvb + (size_t)(wn * 64 + i * 16 + l16) * D_ + quad * 8;
    }

    f32x4 acc[4][4];
#pragma unroll
    for (int i = 0; i < 4; ++i)
#pragma unroll
        for (int j = 0; j < 4; ++j) acc[i][j] = (f32x4){0.f, 0.f, 0.f, 0.f};

    for (int k = 0; k < D_; k += 32) {
        bf16x8 a[4], b[4];
#pragma unroll
        for (int i = 0; i < 4; ++i) a[i] = *(const bf16x8*)(aptr[i] + k);
#pragma unroll
        for (int i = 0; i < 4; ++i) b[i] = *(const bf16x8*)(bptr[i] + k);
#pragma unroll
        for (int i = 0; i < 4; ++i)
#pragma unroll
            for (int j = 0; j < 4; ++j)
                acc[i][j] = __builtin_amdgcn_mfma_f32_16x16x32_bf16(
                    a[i], b[j], acc[i][j], 0, 0, 0);
    }

#pragma unroll
    for (int i = 0; i < 4; ++i)
#pragma unroll
        for (int j = 0; j < 4; ++j)
#pragma unroll
            for (int r = 0; r < 4; ++r) {
                int rl = wm * 64 + i * 16 + quad * 4 + r;
                int cl = j * 16 + l16;
                tile[wn][rl][cl] = acc[i][j][r];
            }
    __syncthreads();

    for (int e = tid; e < 128 * 64; e += 256) {
        int rl = e >> 6, s = e & 63;
        float kk = tile[0][rl][s];
        float vv = tile[1][rl][s];
        float sig = 1.f / (1.f + __expf(-kk));
        float res = __expf(-__expf(time_first[s]) * sig) * vv;
        wkv[(size_t)(bm0 + rl) * S_ + s] = res;
    }
}

// ---------------- K4: linear recurrence over T ------------------------------
__global__ void k4_scan(const float* __restrict__ wkv,
                        const float* __restrict__ time_decay,
                        uint16_t* __restrict__ stb,
                        float* __restrict__ last_state)
{
    const int s = threadIdx.x;
    const int b = blockIdx.x;
    float w = expf(time_decay[s]);
    const float* src = wkv + (size_t)b * T_ * S_ + s;
    uint16_t* dst = stb + (size_t)b * T_ * S_ + s;
    float st = 0.f;
    for (int t = 0; t < T_; ++t) {
        st = st * w + src[(size_t)t * S_];
        dst[(size_t)t * S_] = f2bf(st);
    }
    last_state[b * S_ + s] = st;
}

// ---------------- K5: output = states @ Wout^T  (M=32768, N=1024, K=64) ----
__global__ __launch_bounds__(256) void k5_out(
    const uint16_t* __restrict__ st, const uint16_t* __restrict__ Wob,
    float* __restrict__ out)
{
    const int tid = threadIdx.x;
    const int w = tid >> 6, lane = tid & 63, quad = lane >> 4, l16 = lane & 15;
    const int wm = w >> 1, wn = w & 1;
    const int m0 = blockIdx.y * 128 + wm * 64;
    const int n0 = blockIdx.x * 128 + wn * 64;

    f32x4 acc[4][4];
#pragma unroll
    for (int i = 0; i < 4; ++i)
#pragma unroll
        for (int j = 0; j < 4; ++j) acc[i][j] = (f32x4){0.f, 0.f, 0.f, 0.f};

#pragma unroll
    for (int k = 0; k < S_; k += 32) {
        bf16x8 a[4], b[4];
#pragma unroll
        for (int i = 0; i < 4; ++i)
            a[i] = *(const bf16x8*)(st + (size_t)(m0 + i * 16 + l16) * S_ + k + quad * 8);
#pragma unroll
        for (int i = 0; i < 4; ++i)
            b[i] = *(const bf16x8*)(Wob + (size_t)(n0 + i * 16 + l16) * S_ + k + quad * 8);
#pragma unroll
        for (int i = 0; i < 4; ++i)
#pragma unroll
            for (int j = 0; j < 4; ++j)
                acc[i][j] = __builtin_amdgcn_mfma_f32_16x16x32_bf16(
                    a[i], b[j], acc[i][j], 0, 0, 0);
    }

#pragma unroll
    for (int j = 0; j < 4; ++j) {
        int col = n0 + j * 16 + l16;
#pragma unroll
        for (int i = 0; i < 4; ++i) {
            int row = m0 + i * 16 + quad * 4;
#pragma unroll
            for (int r = 0; r < 4; ++r)
                out[(size_t)(row + r) * D_ + col] = acc[i][j][r];
        }
    }
}

extern "C" void kernel_launch(void* const* d_in, const int* in_sizes, int n_in,
                              void* d_out, int out_size, void* d_ws, size_t ws_size,
                              hipStream_t stream) {
    const float* x          = (const float*)d_in[0];
    const float* time_decay = (const float*)d_in[1];
    const float* time_first = (const float*)d_in[2];
    const float* W_key      = (const float*)d_in[3];
    const float* W_value    = (const float*)d_in[4];
    const float* W_output   = (const float*)d_in[5];
    const float* W_shift    = (const float*)d_in[6];
    const float* shift_gate = (const float*)d_in[7];
    const float* ln_w       = (const float*)d_in[8];
    const float* ln_b       = (const float*)d_in[9];
    float* out = (float*)d_out;

    char* ws = (char*)d_ws;
    // layout (bytes):
    uint16_t* xb   = (uint16_t*)(ws + 0);           // N*D bf16   = 64 MB
    uint16_t* xs   = (uint16_t*)(ws + 67108864);    // N*D bf16   = 64 MB
    float*    wkv  = (float*)   (ws + 134217728);   // N*S f32    =  8 MB
    uint16_t* stb  = (uint16_t*)(ws + 142606336);   // N*S bf16   =  4 MB
    uint16_t* Wsb  = (uint16_t*)(ws + 146800640);   // D*D bf16   =  2 MB
    uint16_t* Wkvb = (uint16_t*)(ws + 148897792);   // 128*D bf16 = 256 KB
    uint16_t* Wob  = (uint16_t*)(ws + 149159936);   // D*S bf16   = 128 KB

    // casts
    cast_f32_bf16<<<32768, 256, 0, stream>>>(x, xb, OUT_ELEMS / 4);
    cast_f32_bf16<<<1024, 256, 0, stream>>>(W_shift, Wsb, (D_ * D_) / 4);
    cast_f32_bf16<<<64, 256, 0, stream>>>(W_key, Wkvb, (S_ * D_) / 4);
    cast_f32_bf16<<<64, 256, 0, stream>>>(W_value, Wkvb + S_ * D_, (S_ * D_) / 4);
    cast_f32_bf16<<<64, 256, 0, stream>>>(W_output, Wob, (D_ * S_) / 4);

    k1_shift_gemm<<<dim3(8, 256), 256, 0, stream>>>(xb, Wsb, shift_gate, xs);
    k2_ln<<<32768, 256, 0, stream>>>(xs, ln_w, ln_b);
    k3_kv<<<256, 256, 0, stream>>>(xs, Wkvb, time_first, wkv);
    k4_scan<<<B_, S_, 0, stream>>>(wkv, time_decay, stb, out + OUT_ELEMS);
    k5_out<<<dim3(8, 256), 256, 0, stream>>>(stb, Wob, out);
}

// Round 2
// 445.335 us; speedup vs baseline: 1.9255x; 1.9255x over previous
//
#include <hip/hip_runtime.h>
#include <stdint.h>

// Problem constants (fixed by setup_inputs)
#define B_ 8
#define T_ 4096
#define D_ 1024
#define S_ 64
#define N_ 32768            // B*T
#define OUT_ELEMS 33554432  // N*D
#define NCHK 128            // scan chunks per batch
#define CHKL 32             // T_/NCHK

typedef __attribute__((ext_vector_type(8))) short bf16x8;
typedef __attribute__((ext_vector_type(8))) unsigned short u16x8;
typedef __attribute__((ext_vector_type(4))) float f32x4;

__device__ __forceinline__ uint16_t f2bf(float f) {
    union { float f; uint32_t u; } v; v.f = f;
    uint32_t r = v.u + 0x7FFFu + ((v.u >> 16) & 1u);
    return (uint16_t)(r >> 16);
}
__device__ __forceinline__ float bf2f(uint16_t h) {
    union { uint32_t u; float f; } v; v.u = ((uint32_t)h) << 16;
    return v.f;
}

// async global->LDS, 16B per lane; LDS dest = uniform base + lane*16
#define GLOAD_LDS16(gp, lp)                                             \
    __builtin_amdgcn_global_load_lds(                                   \
        (const __attribute__((address_space(1))) void*)(gp),            \
        (__attribute__((address_space(3))) void*)(lp), 16, 0, 0)

// ---------------- cast fp32 -> bf16, vectorized ----------------------------
__global__ void cast_f32_bf16(const float* __restrict__ src,
                              uint16_t* __restrict__ dst, int n4) {
    int i = blockIdx.x * blockDim.x + threadIdx.x;
    if (i >= n4) return;
    float4 v = ((const float4*)src)[i];
    ushort4 o;
    o.x = f2bf(v.x); o.y = f2bf(v.y); o.z = f2bf(v.z); o.w = f2bf(v.w);
    ((ushort4*)dst)[i] = o;
}

// ---------------- K1: x_shift = (x_cat @ Wshift^T)*g + x*(1-g)  -> bf16 ----
// m97-style: 128x128 tile, BK=64, global_load_lds(16B) staging, swizzled LDS.
// grid (8, 256): x = N-tile, y = M-tile. 256 threads = 4 waves (2x2 quadrants).
__global__ __launch_bounds__(256) void k1_shift_gemm(
    const uint16_t* __restrict__ xb, const uint16_t* __restrict__ Wsb,
    const float* __restrict__ shift_gate, uint16_t* __restrict__ xs)
{
    __shared__ uint16_t As[128][64];   // 16 KB, row = 128 B = 8 chunks of 16 B
    __shared__ uint16_t Bs[128][64];   // 16 KB
    const int tid = threadIdx.x;
    const int w = tid >> 6, lane = tid & 63, quad = lane >> 4, l16 = lane & 15;
    const int wm = w >> 1, wn = w & 1;
    const int m0 = blockIdx.y * 128;
    const int n0 = blockIdx.x * 128;
    const int m0x = m0 ^ 2048;         // x_cat[t] = x[t ^ T/2]; tile never straddles

    // staging geometry: per instr a wave covers 8 rows x 8 chunks.
    // LDS[row][c] holds global chunk cg = c ^ (row&7)  (bank de-alias swizzle)
    const int srow = w * 32 + (lane >> 3);                 // + i*8 per instr
    const int scg  = ((lane & 7) ^ (lane >> 3)) * 8;       // swizzled global chunk (elems)
    const uint16_t* aG = xb  + (size_t)(m0x + srow) * D_ + scg;
    const uint16_t* bG = Wsb + (size_t)(n0  + srow) * D_ + scg;

    f32x4 acc[4][4];
#pragma unroll
    for (int i = 0; i < 4; ++i)
#pragma unroll
        for (int j = 0; j < 4; ++j) acc[i][j] = (f32x4){0.f, 0.f, 0.f, 0.f};

    for (int k0 = 0; k0 < D_; k0 += 64) {
        __syncthreads();   // previous compute done before overwrite
#pragma unroll
        for (int i = 0; i < 4; ++i) {
            GLOAD_LDS16(aG + k0 + (size_t)(i * 8) * D_, &As[w * 32 + i * 8][0]);
            GLOAD_LDS16(bG + k0 + (size_t)(i * 8) * D_, &Bs[w * 32 + i * 8][0]);
        }
        __syncthreads();   // staging visible (syncthreads drains vmcnt)
#pragma unroll
        for (int ks = 0; ks < 2; ++ks) {
            bf16x8 a[4], b[4];
#pragma unroll
            for (int i = 0; i < 4; ++i) {
                int ra = wm * 64 + i * 16 + l16;
                a[i] = *(const bf16x8*)&As[ra][(((ks * 4 + quad) ^ (l16 & 7)) * 8)];
            }
#pragma unroll
            for (int j = 0; j < 4; ++j) {
                int rb = wn * 64 + j * 16 + l16;
                b[j] = *(const bf16x8*)&Bs[rb][(((ks * 4 + quad) ^ (l16 & 7)) * 8)];
            }
#pragma unroll
            for (int i = 0; i < 4; ++i)
#pragma unroll
                for (int j = 0; j < 4; ++j)
                    acc[i][j] = __builtin_amdgcn_mfma_f32_16x16x32_bf16(
                        a[i], b[j], acc[i][j], 0, 0, 0);
        }
    }

#pragma unroll
    for (int j = 0; j < 4; ++j) {
        int col = n0 + wn * 64 + j * 16 + l16;
        float g = 1.f / (1.f + __expf(-shift_gate[col]));
        float omg = 1.f - g;
#pragma unroll
        for (int i = 0; i < 4; ++i) {
            int row = m0 + wm * 64 + i * 16 + quad * 4;
#pragma unroll
            for (int r = 0; r < 4; ++r) {
                float res = acc[i][j][r] * g +
                            bf2f(xb[(size_t)(row + r) * D_ + col]) * omg;
                xs[(size_t)(row + r) * D_ + col] = f2bf(res);
            }
        }
    }
}

// ---------------- K2: layernorm in-place on xs (bf16), wave-per-row --------
__global__ __launch_bounds__(256) void k2_ln(uint16_t* __restrict__ xs,
                                             const float* __restrict__ ln_w,
                                             const float* __restrict__ ln_b)
{
    const int w = threadIdx.x >> 6, lane = threadIdx.x & 63;
    const size_t row = (size_t)blockIdx.x * 4 + w;
    uint16_t* p = xs + row * D_ + lane * 16;

    u16x8 h0 = *(const u16x8*)p;
    u16x8 h1 = *(const u16x8*)(p + 8);
    float v[16];
#pragma unroll
    for (int i = 0; i < 8; ++i) { v[i] = bf2f(h0[i]); v[8 + i] = bf2f(h1[i]); }
    float s = 0.f, q = 0.f;
#pragma unroll
    for (int i = 0; i < 16; ++i) { s += v[i]; q += v[i] * v[i]; }
#pragma unroll
    for (int off = 32; off > 0; off >>= 1) {
        s += __shfl_xor(s, off);
        q += __shfl_xor(q, off);
    }
    float mu = s * (1.f / D_);
    float var = q * (1.f / D_) - mu * mu;
    float rstd = rsqrtf(var + 1e-5f);

    const float* lw = ln_w + lane * 16;
    const float* lb = ln_b + lane * 16;
    u16x8 o0, o1;
#pragma unroll
    for (int i = 0; i < 8; ++i) {
        o0[i] = f2bf((v[i] - mu) * rstd * lw[i] + lb[i]);
        o1[i] = f2bf((v[8 + i] - mu) * rstd * lw[8 + i] + lb[8 + i]);
    }
    *(u16x8*)p = o0;
    *(u16x8*)(p + 8) = o1;
}

// ---------------- K3: k/v projection + wkv  (M=32768, N=128, K=1024) -------
__global__ __launch_bounds__(256) void k3_kv(
    const uint16_t* __restrict__ xn, const uint16_t* __restrict__ Wkvb,
    const float* __restrict__ time_first, float* __restrict__ wkv)
{
    __shared__ float tile[2][128][65];
    const int tid = threadIdx.x;
    const int w = tid >> 6, lane = tid & 63, quad = lane >> 4, l16 = lane & 15;
    const int wm = w >> 1, wn = w & 1;
    const int bm0 = blockIdx.x * 128;
    const int m0 = bm0 + wm * 64;

    const uint16_t* aptr[4];
    const uint16_t* bptr[4];
#pragma unroll
    for (int i = 0; i < 4; ++i) {
        aptr[i] = xn + (size_t)(m0 + i * 16 + l16) * D_ + quad * 8;
        bptr[i] = Wkvb + (size_t)(wn * 64 + i * 16 + l16) * D_ + quad * 8;
    }

    f32x4 acc[4][4];
#pragma unroll
    for (int i = 0; i < 4; ++i)
#pragma unroll
        for (int j = 0; j < 4; ++j) acc[i][j] = (f32x4){0.f, 0.f, 0.f, 0.f};

    for (int k = 0; k < D_; k += 32) {
        bf16x8 a[4], b[4];
#pragma unroll
        for (int i = 0; i < 4; ++i) a[i] = *(const bf16x8*)(aptr[i] + k);
#pragma unroll
        for (int i = 0; i < 4; ++i) b[i] = *(const bf16x8*)(bptr[i] + k);
#pragma unroll
        for (int i = 0; i < 4; ++i)
#pragma unroll
            for (int j = 0; j < 4; ++j)
                acc[i][j] = __builtin_amdgcn_mfma_f32_16x16x32_bf16(
                    a[i], b[j], acc[i][j], 0, 0, 0);
    }

#pragma unroll
    for (int i = 0; i < 4; ++i)
#pragma unroll
        for (int j = 0; j < 4; ++j)
#pragma unroll
            for (int r = 0; r < 4; ++r) {
                int rl = wm * 64 + i * 16 + quad * 4 + r;
                int cl = j * 16 + l16;
                tile[wn][rl][cl] = acc[i][j][r];
            }
    __syncthreads();

    for (int e = tid; e < 128 * 64; e += 256) {
        int rl = e >> 6, s = e & 63;
        float kk = tile[0][rl][s];
        float vv = tile[1][rl][s];
        float sig = 1.f / (1.f + __expf(-kk));
        float res = __expf(-__expf(time_first[s]) * sig) * vv;
        wkv[(size_t)(bm0 + rl) * S_ + s] = res;
    }
}

// ---------------- K4: chunked linear recurrence (3 phases) ------------------
// phase A: per-chunk partial scans (init 0)
__global__ void k4a(const float* __restrict__ wkv,
                    const float* __restrict__ time_decay,
                    float* __restrict__ part)
{
    const int s = threadIdx.x;
    const int bc = blockIdx.x;             // b*NCHK + c
    const int b = bc >> 7, c = bc & (NCHK - 1);
    float w = expf(time_decay[s]);
    const float* src = wkv + ((size_t)b * T_ + c * CHKL) * S_ + s;
    float st = 0.f;
    for (int t = 0; t < CHKL; ++t) st = st * w + src[(size_t)t * S_];
    part[(size_t)bc * S_ + s] = st;
}
// phase B: serial carry combine over chunks (tiny)
__global__ void k4b(const float* __restrict__ part,
                    const float* __restrict__ time_decay,
                    float* __restrict__ carry)
{
    const int s = threadIdx.x;
    const int b = blockIdx.x;
    float wL = expf(time_decay[s] * (float)CHKL);
    float cin = 0.f;
    for (int c = 0; c < NCHK; ++c) {
        size_t idx = ((size_t)b * NCHK + c) * S_ + s;
        carry[idx] = cin;                  // carry INTO chunk c
        cin = cin * wL + part[idx];
    }
}
// phase C: re-scan chunks with carry-in, write states (bf16) + last_state
__global__ void k4c(const float* __restrict__ wkv,
                    const float* __restrict__ time_decay,
                    const float* __restrict__ carry,
                    uint16_t* __restrict__ stb,
                    float* __restrict__ last_state)
{
    const int s = threadIdx.x;
    const int bc = blockIdx.x;
    const int b = bc >> 7, c = bc & (NCHK - 1);
    float w = expf(time_decay[s]);
    const float* src = wkv + ((size_t)b * T_ + c * CHKL) * S_ + s;
    uint16_t* dst = stb + ((size_t)b * T_ + c * CHKL) * S_ + s;
    float st = carry[(size_t)bc * S_ + s];
    for (int t = 0; t < CHKL; ++t) {
        st = st * w + src[(size_t)t * S_];
        dst[(size_t)t * S_] = f2bf(st);
    }
    if (c == NCHK - 1) last_state[b * S_ + s] = st;
}

// ---------------- K5: output = states @ Wout^T  (M=32768, N=1024, K=64) ----
__global__ __launch_bounds__(256) void k5_out(
    const uint16_t* __restrict__ st, const uint16_t* __restrict__ Wob,
    float* __restrict__ out)
{
    const int tid = threadIdx.x;
    const int w = tid >> 6, lane = tid & 63, quad = lane >> 4, l16 = lane & 15;
    const int wm = w >> 1, wn = w & 1;
    const int m0 = blockIdx.y * 128 + wm * 64;
    const int n0 = blockIdx.x * 128 + wn * 64;

    f32x4 acc[4][4];
#pragma unroll
    for (int i = 0; i < 4; ++i)
#pragma unroll
        for (int j = 0; j < 4; ++j) acc[i][j] = (f32x4){0.f, 0.f, 0.f, 0.f};

#pragma unroll
    for (int k = 0; k < S_; k += 32) {
        bf16x8 a[4], b[4];
#pragma unroll
        for (int i = 0; i < 4; ++i)
            a[i] = *(const bf16x8*)(st + (size_t)(m0 + i * 16 + l16) * S_ + k + quad * 8);
#pragma unroll
        for (int i = 0; i < 4; ++i)
            b[i] = *(const bf16x8*)(Wob + (size_t)(n0 + i * 16 + l16) * S_ + k + quad * 8);
#pragma unroll
        for (int i = 0; i < 4; ++i)
#pragma unroll
            for (int j = 0; j < 4; ++j)
                acc[i][j] = __builtin_amdgcn_mfma_f32_16x16x32_bf16(
                    a[i], b[j], acc[i][j], 0, 0, 0);
    }

#pragma unroll
    for (int j = 0; j < 4; ++j) {
        int col = n0 + j * 16 + l16;
#pragma unroll
        for (int i = 0; i < 4; ++i) {
            int row = m0 + i * 16 + quad * 4;
#pragma unroll
            for (int r = 0; r < 4; ++r)
                out[(size_t)(row + r) * D_ + col] = acc[i][j][r];
        }
    }
}

extern "C" void kernel_launch(void* const* d_in, const int* in_sizes, int n_in,
                              void* d_out, int out_size, void* d_ws, size_t ws_size,
                              hipStream_t stream) {
    const float* x          = (const float*)d_in[0];
    const float* time_decay = (const float*)d_in[1];
    const float* time_first = (const float*)d_in[2];
    const float* W_key      = (const float*)d_in[3];
    const float* W_value    = (const float*)d_in[4];
    const float* W_output   = (const float*)d_in[5];
    const float* W_shift    = (const float*)d_in[6];
    const float* shift_gate = (const float*)d_in[7];
    const float* ln_w       = (const float*)d_in[8];
    const float* ln_b       = (const float*)d_in[9];
    float* out = (float*)d_out;

    char* ws = (char*)d_ws;
    // layout (bytes):
    uint16_t* xb   = (uint16_t*)(ws + 0);           // N*D bf16   = 64 MB
    uint16_t* xs   = (uint16_t*)(ws + 67108864);    // N*D bf16   = 64 MB
    float*    wkv  = (float*)   (ws + 134217728);   // N*S f32    =  8 MB
    uint16_t* stb  = (uint16_t*)(ws + 142606336);   // N*S bf16   =  4 MB
    uint16_t* Wsb  = (uint16_t*)(ws + 146800640);   // D*D bf16   =  2 MB
    uint16_t* Wkvb = (uint16_t*)(ws + 148897792);   // 128*D bf16 = 256 KB
    uint16_t* Wob  = (uint16_t*)(ws + 149159936);   // D*S bf16   = 128 KB
    float*    part = (float*)   (ws + 149291008);   // B*NCHK*S   = 256 KB
    float*    carry= (float*)   (ws + 149553152);   // B*NCHK*S   = 256 KB

    // casts
    cast_f32_bf16<<<32768, 256, 0, stream>>>(x, xb, OUT_ELEMS / 4);
    cast_f32_bf16<<<1024, 256, 0, stream>>>(W_shift, Wsb, (D_ * D_) / 4);
    cast_f32_bf16<<<64, 256, 0, stream>>>(W_key, Wkvb, (S_ * D_) / 4);
    cast_f32_bf16<<<64, 256, 0, stream>>>(W_value, Wkvb + S_ * D_, (S_ * D_) / 4);
    cast_f32_bf16<<<64, 256, 0, stream>>>(W_output, Wob, (D_ * S_) / 4);

    k1_shift_gemm<<<dim3(8, 256), 256, 0, stream>>>(xb, Wsb, shift_gate, xs);
    k2_ln<<<N_ / 4, 256, 0, stream>>>(xs, ln_w, ln_b);
    k3_kv<<<256, 256, 0, stream>>>(xs, Wkvb, time_first, wkv);
    k4a<<<B_ * NCHK, S_, 0, stream>>>(wkv, time_decay, part);
    k4b<<<B_, S_, 0, stream>>>(part, time_decay, carry);
    k4c<<<B_ * NCHK, S_, 0, stream>>>(wkv, time_decay, carry, stb, out + OUT_ELEMS);
    k5_out<<<dim3(8, 256), 256, 0, stream>>>(stb, Wob, out);
}

// Round 3
// 430.893 us; speedup vs baseline: 1.9901x; 1.0335x over previous
//
#include <hip/hip_runtime.h>
#include <stdint.h>

// Problem constants (fixed by setup_inputs)
#define B_ 8
#define T_ 4096
#define D_ 1024
#define S_ 64
#define N_ 32768            // B*T
#define OUT_ELEMS 33554432  // N*D
#define NCHK 128            // scan chunks per batch
#define CHKL 32             // T_/NCHK

typedef __attribute__((ext_vector_type(8))) short bf16x8;
typedef __attribute__((ext_vector_type(8))) unsigned short u16x8;
typedef __attribute__((ext_vector_type(4))) float f32x4;

__device__ __forceinline__ uint16_t f2bf(float f) {
    union { float f; uint32_t u; } v; v.f = f;
    uint32_t r = v.u + 0x7FFFu + ((v.u >> 16) & 1u);
    return (uint16_t)(r >> 16);
}
__device__ __forceinline__ float bf2f(uint16_t h) {
    union { uint32_t u; float f; } v; v.u = ((uint32_t)h) << 16;
    return v.f;
}

// async global->LDS, 16B per lane; LDS dest = wave-uniform base + lane*16
#define GLOAD_LDS16(gp, lp)                                             \
    __builtin_amdgcn_global_load_lds(                                   \
        (const __attribute__((address_space(1))) void*)(gp),            \
        (__attribute__((address_space(3))) void*)(lp), 16, 0, 0)

// ---------------- cast fp32 -> bf16 (x only) --------------------------------
__global__ void cast_f32_bf16(const float* __restrict__ src,
                              uint16_t* __restrict__ dst, int n4) {
    int i = blockIdx.x * blockDim.x + threadIdx.x;
    if (i >= n4) return;
    float4 v = ((const float4*)src)[i];
    ushort4 o;
    o.x = f2bf(v.x); o.y = f2bf(v.y); o.z = f2bf(v.z); o.w = f2bf(v.w);
    ((ushort4*)dst)[i] = o;
}

// ---------------- fused weight prep: casts + sigmoid(gate) + exp(tf) -------
// float4 ranges: [0,262144) Wshift | +16384 Wkey | +16384 Wval | +16384 Wout
//                | +256 gbuf | +16 efirst
__global__ void wprep(const float* __restrict__ Wsf, const float* __restrict__ Wkf,
                      const float* __restrict__ Wvf, const float* __restrict__ Wof,
                      const float* __restrict__ sg, const float* __restrict__ tf,
                      uint16_t* __restrict__ Wsb, uint16_t* __restrict__ Wkvb,
                      uint16_t* __restrict__ Wob, float* __restrict__ gbuf,
                      float* __restrict__ efirst)
{
    int i = blockIdx.x * blockDim.x + threadIdx.x;
    const float* src; uint16_t* dst; int j;
    if (i < 262144) { src = Wsf; dst = Wsb; j = i; }
    else if (i < 278528) { src = Wkf; dst = Wkvb; j = i - 262144; }
    else if (i < 294912) { src = Wvf; dst = Wkvb + 65536; j = i - 278528; }
    else if (i < 311296) { src = Wof; dst = Wob; j = i - 294912; }
    else if (i < 311552) {
        j = i - 311296;
        float4 v = ((const float4*)sg)[j];
        float4 g;
        g.x = 1.f / (1.f + __expf(-v.x)); g.y = 1.f / (1.f + __expf(-v.y));
        g.z = 1.f / (1.f + __expf(-v.z)); g.w = 1.f / (1.f + __expf(-v.w));
        ((float4*)gbuf)[j] = g;
        return;
    } else if (i < 311568) {
        j = i - 311552;
        float4 v = ((const float4*)tf)[j];
        float4 e;
        e.x = __expf(v.x); e.y = __expf(v.y); e.z = __expf(v.z); e.w = __expf(v.w);
        ((float4*)efirst)[j] = e;
        return;
    } else return;
    float4 v = ((const float4*)src)[j];
    ushort4 o;
    o.x = f2bf(v.x); o.y = f2bf(v.y); o.z = f2bf(v.z); o.w = f2bf(v.w);
    ((ushort4*)dst)[j] = o;
}

// ---------------- K1: x_shift = (x_cat @ Wshift^T)*g + x*(1-g)  -> bf16 ----
// 128x128 tile, BK=64, global_load_lds(16B), swizzled LDS, XCD-local m-ranges.
__global__ __launch_bounds__(256) void k1_shift_gemm(
    const uint16_t* __restrict__ xb, const uint16_t* __restrict__ Wsb,
    const float* __restrict__ gbuf, uint16_t* __restrict__ xs)
{
    __shared__ char sh[34816];
    uint16_t (*As)[64] = (uint16_t(*)[64])sh;            // [128][64] bf16
    uint16_t (*Bs)[64] = (uint16_t(*)[64])(sh + 16384);  // [128][64]
    float (*epi)[68] = (float(*)[68])sh;                 // [128][68] f32 (union)

    const int tid = threadIdx.x;
    const int w = tid >> 6, lane = tid & 63, quad = lane >> 4, l16 = lane & 15;
    const int wm = w >> 1, wn = w & 1;
    // XCD swizzle: assume consecutive blocks round-robin XCDs (lin&7 = XCD).
    // XCD x owns m-tiles [x*32, x*32+32): A rows stay in that XCD's L2.
    const int lin = blockIdx.x;
    const int mt = (lin & 7) * 32 + (lin >> 6);
    const int nt = (lin >> 3) & 7;
    const int m0 = mt * 128, n0 = nt * 128;
    const int m0x = m0 ^ 2048;         // x_cat[t] = x[t ^ T/2]; tile never straddles

    const int srow = w * 32 + (lane >> 3);
    const int scg  = ((lane & 7) ^ ((lane >> 3) & 7)) * 8;
    const uint16_t* aG = xb  + (size_t)(m0x + srow) * D_ + scg;
    const uint16_t* bG = Wsb + (size_t)(n0  + srow) * D_ + scg;

    f32x4 acc[4][4];
#pragma unroll
    for (int i = 0; i < 4; ++i)
#pragma unroll
        for (int j = 0; j < 4; ++j) acc[i][j] = (f32x4){0.f, 0.f, 0.f, 0.f};

    for (int k0 = 0; k0 < D_; k0 += 64) {
        __syncthreads();
#pragma unroll
        for (int i = 0; i < 4; ++i) {
            GLOAD_LDS16(aG + k0 + (size_t)(i * 8) * D_, &As[w * 32 + i * 8][0]);
            GLOAD_LDS16(bG + k0 + (size_t)(i * 8) * D_, &Bs[w * 32 + i * 8][0]);
        }
        __syncthreads();
#pragma unroll
        for (int ks = 0; ks < 2; ++ks) {
            bf16x8 a[4], b[4];
#pragma unroll
            for (int i = 0; i < 4; ++i)
                a[i] = *(const bf16x8*)&As[wm * 64 + i * 16 + l16]
                                         [(((ks * 4 + quad) ^ (l16 & 7)) * 8)];
#pragma unroll
            for (int j = 0; j < 4; ++j)
                b[j] = *(const bf16x8*)&Bs[wn * 64 + j * 16 + l16]
                                         [(((ks * 4 + quad) ^ (l16 & 7)) * 8)];
#pragma unroll
            for (int i = 0; i < 4; ++i)
#pragma unroll
                for (int j = 0; j < 4; ++j)
                    acc[i][j] = __builtin_amdgcn_mfma_f32_16x16x32_bf16(
                        a[i], b[j], acc[i][j], 0, 0, 0);
        }
    }

    // epilogue: two 64-col passes through LDS, vectorized global I/O
    const int row = tid >> 1;
    const int c0 = (tid & 1) * 32;
#pragma unroll
    for (int h = 0; h < 2; ++h) {
        __syncthreads();
        if (wn == h) {
#pragma unroll
            for (int i = 0; i < 4; ++i)
#pragma unroll
                for (int j = 0; j < 4; ++j)
#pragma unroll
                    for (int r = 0; r < 4; ++r)
                        epi[wm * 64 + i * 16 + quad * 4 + r][j * 16 + l16] =
                            acc[i][j][r];
        }
        __syncthreads();
        const int col = n0 + h * 64 + c0;
        const uint16_t* xrow = xb + (size_t)(m0 + row) * D_ + col;
        uint16_t* orow = xs + (size_t)(m0 + row) * D_ + col;
#pragma unroll
        for (int c4 = 0; c4 < 8; ++c4) {
            float4 g4 = ((const float4*)(gbuf + col))[c4];
            ushort4 xh = ((const ushort4*)xrow)[c4];
            const float* e = &epi[row][c0 + c4 * 4];
            ushort4 o;
            o.x = f2bf(e[0] * g4.x + bf2f(xh.x) * (1.f - g4.x));
            o.y = f2bf(e[1] * g4.y + bf2f(xh.y) * (1.f - g4.y));
            o.z = f2bf(e[2] * g4.z + bf2f(xh.z) * (1.f - g4.z));
            o.w = f2bf(e[3] * g4.w + bf2f(xh.w) * (1.f - g4.w));
            ((ushort4*)orow)[c4] = o;
        }
    }
}

// ---------------- K2: layernorm in-place on xs (bf16), wave-per-row --------
__global__ __launch_bounds__(256) void k2_ln(uint16_t* __restrict__ xs,
                                             const float* __restrict__ ln_w,
                                             const float* __restrict__ ln_b)
{
    const int w = threadIdx.x >> 6, lane = threadIdx.x & 63;
    const size_t row = (size_t)blockIdx.x * 4 + w;
    uint16_t* p = xs + row * D_ + lane * 16;

    u16x8 h0 = *(const u16x8*)p;
    u16x8 h1 = *(const u16x8*)(p + 8);
    float v[16];
#pragma unroll
    for (int i = 0; i < 8; ++i) { v[i] = bf2f(h0[i]); v[8 + i] = bf2f(h1[i]); }
    float s = 0.f, q = 0.f;
#pragma unroll
    for (int i = 0; i < 16; ++i) { s += v[i]; q += v[i] * v[i]; }
#pragma unroll
    for (int off = 32; off > 0; off >>= 1) {
        s += __shfl_xor(s, off);
        q += __shfl_xor(q, off);
    }
    float mu = s * (1.f / D_);
    float var = q * (1.f / D_) - mu * mu;
    float rstd = rsqrtf(var + 1e-5f);

    const float* lw = ln_w + lane * 16;
    const float* lb = ln_b + lane * 16;
    u16x8 o0, o1;
#pragma unroll
    for (int i = 0; i < 8; ++i) {
        o0[i] = f2bf((v[i] - mu) * rstd * lw[i] + lb[i]);
        o1[i] = f2bf((v[8 + i] - mu) * rstd * lw[8 + i] + lb[8 + i]);
    }
    *(u16x8*)p = o0;
    *(u16x8*)(p + 8) = o1;
}

// ---------------- K3: k/v projection + wkv, staged (64x128 tile) -----------
// grid 512 blocks; Wkvb rows 0..63 = W_key, 64..127 = W_value.
__global__ __launch_bounds__(256) void k3_kv(
    const uint16_t* __restrict__ xn, const uint16_t* __restrict__ Wkvb,
    const float* __restrict__ efirst, float* __restrict__ wkv)
{
    __shared__ char sh[33792];
    uint16_t (*As)[64] = (uint16_t(*)[64])sh;           // [64][64]  8 KB
    uint16_t (*Bs)[64] = (uint16_t(*)[64])(sh + 8192);  // [128][64] 16 KB
    float (*epi)[132] = (float(*)[132])sh;              // [64][132] f32 (union)

    const int tid = threadIdx.x;
    const int w = tid >> 6, lane = tid & 63, quad = lane >> 4, l16 = lane & 15;
    const int wm = w >> 1, wn = w & 1;
    const int m0 = blockIdx.x * 64;

    const int lrow = w * 8 + (lane >> 3);
    const int scg  = ((lane & 7) ^ ((lane >> 3) & 7)) * 8;
    const uint16_t* aG = xn + (size_t)(m0 + lrow) * D_ + scg;
    const uint16_t* bG = Wkvb + (size_t)lrow * D_ + scg;

    f32x4 acc[2][4];
#pragma unroll
    for (int i = 0; i < 2; ++i)
#pragma unroll
        for (int j = 0; j < 4; ++j) acc[i][j] = (f32x4){0.f, 0.f, 0.f, 0.f};

    for (int k0 = 0; k0 < D_; k0 += 64) {
        __syncthreads();
#pragma unroll
        for (int i = 0; i < 2; ++i)
            GLOAD_LDS16(aG + k0 + (size_t)(i * 32) * D_, &As[lrow - (lane >> 3) + i * 32][0]);
#pragma unroll
        for (int i = 0; i < 4; ++i)
            GLOAD_LDS16(bG + k0 + (size_t)(i * 32) * D_, &Bs[lrow - (lane >> 3) + i * 32][0]);
        __syncthreads();
#pragma unroll
        for (int ks = 0; ks < 2; ++ks) {
            bf16x8 a[2], b[4];
#pragma unroll
            for (int i = 0; i < 2; ++i)
                a[i] = *(const bf16x8*)&As[wm * 32 + i * 16 + l16]
                                         [(((ks * 4 + quad) ^ (l16 & 7)) * 8)];
#pragma unroll
            for (int j = 0; j < 4; ++j)
                b[j] = *(const bf16x8*)&Bs[wn * 64 + j * 16 + l16]
                                         [(((ks * 4 + quad) ^ (l16 & 7)) * 8)];
#pragma unroll
            for (int i = 0; i < 2; ++i)
#pragma unroll
                for (int j = 0; j < 4; ++j)
                    acc[i][j] = __builtin_amdgcn_mfma_f32_16x16x32_bf16(
                        a[i], b[j], acc[i][j], 0, 0, 0);
        }
    }

    __syncthreads();
#pragma unroll
    for (int i = 0; i < 2; ++i)
#pragma unroll
        for (int j = 0; j < 4; ++j)
#pragma unroll
            for (int r = 0; r < 4; ++r)
                epi[wm * 32 + i * 16 + quad * 4 + r][wn * 64 + j * 16 + l16] =
                    acc[i][j][r];
    __syncthreads();

    // wkv = exp(-exp(tf)*sigmoid(k)) * v ; thread: row=tid>>2, 16 s-cols
    const int row = tid >> 2, s0 = (tid & 3) * 16;
    float* dst = wkv + (size_t)(m0 + row) * S_ + s0;
#pragma unroll
    for (int c4 = 0; c4 < 4; ++c4) {
        float4 kk = *(const float4*)&epi[row][s0 + c4 * 4];
        float4 vv = *(const float4*)&epi[row][64 + s0 + c4 * 4];
        float4 ef = ((const float4*)(efirst + s0))[c4];
        float4 o;
        o.x = __expf(-ef.x / (1.f + __expf(-kk.x))) * vv.x;
        o.y = __expf(-ef.y / (1.f + __expf(-kk.y))) * vv.y;
        o.z = __expf(-ef.z / (1.f + __expf(-kk.z))) * vv.z;
        o.w = __expf(-ef.w / (1.f + __expf(-kk.w))) * vv.w;
        *(float4*)(dst + c4 * 4) = o;
    }
}

// ---------------- K4: chunked linear recurrence (3 phases) ------------------
__global__ void k4a(const float* __restrict__ wkv,
                    const float* __restrict__ time_decay,
                    float* __restrict__ part)
{
    const int s = threadIdx.x;
    const int bc = blockIdx.x;
    const int b = bc >> 7, c = bc & (NCHK - 1);
    float w = expf(time_decay[s]);
    const float* src = wkv + ((size_t)b * T_ + c * CHKL) * S_ + s;
    float st = 0.f;
    for (int t = 0; t < CHKL; ++t) st = st * w + src[(size_t)t * S_];
    part[(size_t)bc * S_ + s] = st;
}
__global__ void k4b(const float* __restrict__ part,
                    const float* __restrict__ time_decay,
                    float* __restrict__ carry)
{
    const int s = threadIdx.x;
    const int b = blockIdx.x;
    float wL = expf(time_decay[s] * (float)CHKL);
    float cin = 0.f;
    for (int c = 0; c < NCHK; ++c) {
        size_t idx = ((size_t)b * NCHK + c) * S_ + s;
        carry[idx] = cin;
        cin = cin * wL + part[idx];
    }
}
__global__ void k4c(const float* __restrict__ wkv,
                    const float* __restrict__ time_decay,
                    const float* __restrict__ carry,
                    uint16_t* __restrict__ stb,
                    float* __restrict__ last_state)
{
    const int s = threadIdx.x;
    const int bc = blockIdx.x;
    const int b = bc >> 7, c = bc & (NCHK - 1);
    float w = expf(time_decay[s]);
    const float* src = wkv + ((size_t)b * T_ + c * CHKL) * S_ + s;
    uint16_t* dst = stb + ((size_t)b * T_ + c * CHKL) * S_ + s;
    float st = carry[(size_t)bc * S_ + s];
    for (int t = 0; t < CHKL; ++t) {
        st = st * w + src[(size_t)t * S_];
        dst[(size_t)t * S_] = f2bf(st);
    }
    if (c == NCHK - 1) last_state[b * S_ + s] = st;
}

// ---------------- K5: output = states @ Wout^T  (M=32768, N=1024, K=64) ----
__global__ __launch_bounds__(256) void k5_out(
    const uint16_t* __restrict__ st, const uint16_t* __restrict__ Wob,
    float* __restrict__ out)
{
    __shared__ float epi[128][68];   // 34 KB
    const int tid = threadIdx.x;
    const int w = tid >> 6, lane = tid & 63, quad = lane >> 4, l16 = lane & 15;
    const int wm = w >> 1, wn = w & 1;
    const int m0b = blockIdx.y * 128;
    const int n0b = blockIdx.x * 128;

    f32x4 acc[4][4];
#pragma unroll
    for (int i = 0; i < 4; ++i)
#pragma unroll
        for (int j = 0; j < 4; ++j) acc[i][j] = (f32x4){0.f, 0.f, 0.f, 0.f};

#pragma unroll
    for (int k = 0; k < S_; k += 32) {
        bf16x8 a[4], b[4];
#pragma unroll
        for (int i = 0; i < 4; ++i)
            a[i] = *(const bf16x8*)(st + (size_t)(m0b + wm * 64 + i * 16 + l16) * S_ + k + quad * 8);
#pragma unroll
        for (int i = 0; i < 4; ++i)
            b[i] = *(const bf16x8*)(Wob + (size_t)(n0b + wn * 64 + i * 16 + l16) * S_ + k + quad * 8);
#pragma unroll
        for (int i = 0; i < 4; ++i)
#pragma unroll
            for (int j = 0; j < 4; ++j)
                acc[i][j] = __builtin_amdgcn_mfma_f32_16x16x32_bf16(
                    a[i], b[j], acc[i][j], 0, 0, 0);
    }

    const int row = tid >> 1;
    const int c0 = (tid & 1) * 32;
#pragma unroll
    for (int h = 0; h < 2; ++h) {
        __syncthreads();
        if (wn == h) {
#pragma unroll
            for (int i = 0; i < 4; ++i)
#pragma unroll
                for (int j = 0; j < 4; ++j)
#pragma unroll
                    for (int r = 0; r < 4; ++r)
                        epi[wm * 64 + i * 16 + quad * 4 + r][j * 16 + l16] =
                            acc[i][j][r];
        }
        __syncthreads();
        float* dst = out + (size_t)(m0b + row) * D_ + n0b + h * 64 + c0;
#pragma unroll
        for (int c4 = 0; c4 < 8; ++c4)
            ((float4*)dst)[c4] = *(const float4*)&epi[row][c0 + c4 * 4];
    }
}

extern "C" void kernel_launch(void* const* d_in, const int* in_sizes, int n_in,
                              void* d_out, int out_size, void* d_ws, size_t ws_size,
                              hipStream_t stream) {
    const float* x          = (const float*)d_in[0];
    const float* time_decay = (const float*)d_in[1];
    const float* time_first = (const float*)d_in[2];
    const float* W_key      = (const float*)d_in[3];
    const float* W_value    = (const float*)d_in[4];
    const float* W_output   = (const float*)d_in[5];
    const float* W_shift    = (const float*)d_in[6];
    const float* shift_gate = (const float*)d_in[7];
    const float* ln_w       = (const float*)d_in[8];
    const float* ln_b       = (const float*)d_in[9];
    float* out = (float*)d_out;

    char* ws = (char*)d_ws;
    uint16_t* xb    = (uint16_t*)(ws + 0);           // N*D bf16   = 64 MB
    uint16_t* xs    = (uint16_t*)(ws + 67108864);    // N*D bf16   = 64 MB
    float*    wkv   = (float*)   (ws + 134217728);   // N*S f32    =  8 MB
    uint16_t* stb   = (uint16_t*)(ws + 142606336);   // N*S bf16   =  4 MB
    uint16_t* Wsb   = (uint16_t*)(ws + 146800640);   // D*D bf16   =  2 MB
    uint16_t* Wkvb  = (uint16_t*)(ws + 148897792);   // 128*D bf16 = 256 KB
    uint16_t* Wob   = (uint16_t*)(ws + 149159936);   // D*S bf16   = 128 KB
    float*    part  = (float*)   (ws + 149291008);   // B*NCHK*S   = 256 KB
    float*    carry = (float*)   (ws + 149553152);   // B*NCHK*S   = 256 KB
    float*    gbuf  = (float*)   (ws + 149815296);   // D f32      =   4 KB
    float*    efirst= (float*)   (ws + 149819392);   // S f32      = 256 B

    cast_f32_bf16<<<32768, 256, 0, stream>>>(x, xb, OUT_ELEMS / 4);
    wprep<<<1218, 256, 0, stream>>>(W_shift, W_key, W_value, W_output,
                                    shift_gate, time_first,
                                    Wsb, Wkvb, Wob, gbuf, efirst);

    k1_shift_gemm<<<2048, 256, 0, stream>>>(xb, Wsb, gbuf, xs);
    k2_ln<<<N_ / 4, 256, 0, stream>>>(xs, ln_w, ln_b);
    k3_kv<<<512, 256, 0, stream>>>(xs, Wkvb, efirst, wkv);
    k4a<<<B_ * NCHK, S_, 0, stream>>>(wkv, time_decay, part);
    k4b<<<B_, S_, 0, stream>>>(part, time_decay, carry);
    k4c<<<B_ * NCHK, S_, 0, stream>>>(wkv, time_decay, carry, stb, out + OUT_ELEMS);
    k5_out<<<dim3(8, 256), 256, 0, stream>>>(stb, Wob, out);
}